// Round 1
// baseline (1146.933 us; speedup 1.0000x reference)
//
#include <hip/hip_runtime.h>
#include <stdint.h>

static inline size_t align256(size_t x) { return (x + 255) & ~size_t(255); }

// ---- edge dtype detection: is the edge_index buffer int32 or int64? ----
__global__ void k_detect(const long long* __restrict__ e, int n_check, int* __restrict__ is32) {
    int i = blockIdx.x * blockDim.x + threadIdx.x;
    if (i < n_check) {
        long long v = e[i];
        if (v < 0 || v > 0x7fffffffLL) atomicOr(is32, 1);
    }
}

// ---- count in-degree on dst ----
__global__ void k_count(const void* __restrict__ eidx, int E, const int* __restrict__ is32,
                        int* __restrict__ counts) {
    int e = blockIdx.x * blockDim.x + threadIdx.x;
    if (e >= E) return;
    int d;
    if (*is32) d = ((const int*)eidx)[(size_t)E + e];
    else       d = (int)((const long long*)eidx)[(size_t)E + e];
    atomicAdd(&counts[d], 1);
}

__global__ void k_dinv(const int* __restrict__ counts, float* __restrict__ dinv, int N) {
    int i = blockIdx.x * blockDim.x + threadIdx.x;
    if (i < N) dinv[i] = rsqrtf((float)counts[i] + 1.0f);
}

// ---- single-block exclusive scan of counts -> row_start[N+1], pos[N] ----
__global__ __launch_bounds__(1024) void k_scan(const int* __restrict__ counts,
                                               int* __restrict__ row_start,
                                               int* __restrict__ pos, int N) {
    __shared__ int swt[16];
    __shared__ int swt2[16];
    const int t = threadIdx.x, lane = t & 63, w = t >> 6;
    int carry = 0;
    for (int base = 0; base < N; base += 1024) {
        int i = base + t;
        int v = (i < N) ? counts[i] : 0;
        int incl = v;
        #pragma unroll
        for (int off = 1; off < 64; off <<= 1) {
            int nbr = __shfl_up(incl, off, 64);
            if (lane >= off) incl += nbr;
        }
        if (lane == 63) swt[w] = incl;
        __syncthreads();
        if (w == 0) {
            int wincl = (lane < 16) ? swt[lane] : 0;
            #pragma unroll
            for (int off = 1; off < 16; off <<= 1) {
                int nbr = __shfl_up(wincl, off, 64);
                if (lane >= off) wincl += nbr;
            }
            if (lane < 16) swt2[lane] = wincl;
        }
        __syncthreads();
        int wave_off = (w == 0) ? 0 : swt2[w - 1];
        int excl = carry + wave_off + incl - v;
        if (i < N) { row_start[i] = excl; pos[i] = excl; }
        carry += swt2[15];
        __syncthreads();
    }
    if (t == 0) row_start[N] = carry;
}

// ---- fill CSR: esrc sorted by dst ----
__global__ void k_fill(const void* __restrict__ eidx, int E, const int* __restrict__ is32,
                       int* __restrict__ pos, int* __restrict__ esrc) {
    int e = blockIdx.x * blockDim.x + threadIdx.x;
    if (e >= E) return;
    int s, d;
    if (*is32) {
        s = ((const int*)eidx)[e];
        d = ((const int*)eidx)[(size_t)E + e];
    } else {
        s = (int)((const long long*)eidx)[e];
        d = (int)((const long long*)eidx)[(size_t)E + e];
    }
    int p = atomicAdd(&pos[d], 1);
    esrc[p] = s;
}

// ---- fp32 GEMM: H[N x M] = X[N x 128] @ W[128 x M]; one block = 48 rows x 64 cols ----
template<int M>
__global__ __launch_bounds__(256) void k_gemm(const float* __restrict__ X,
                                              const float* __restrict__ W,
                                              float* __restrict__ H, int N) {
    constexpr int K  = 128;
    constexpr int TY = 16;
    constexpr int R  = 3;
    constexpr int RB = TY * R;  // 48 rows/block
    __shared__ float Ws[K * 64];   // 32 KB
    __shared__ float Xs[RB * K];   // 24 KB
    const int t  = threadIdx.x;
    const int c0 = blockIdx.y * 64;
    // stage W column-segment [128][64]
    for (int i = t; i < K * 16; i += 256) {
        int k = i >> 4, c4 = i & 15;
        ((float4*)Ws)[k * 16 + c4] = ((const float4*)(W + (size_t)k * M + c0))[c4];
    }
    // stage 48 rows of X
    const int row0 = blockIdx.x * RB;
    for (int i = t; i < RB * 32; i += 256) {
        int r = i >> 5, c = i & 31;
        int row = row0 + r;
        float4 v = make_float4(0.f, 0.f, 0.f, 0.f);
        if (row < N) v = ((const float4*)X)[(size_t)row * 32 + c];
        ((float4*)Xs)[i] = v;
    }
    __syncthreads();
    const int tx = t & 15, ty = t >> 4;
    float4 acc[R];
    #pragma unroll
    for (int r = 0; r < R; ++r) acc[r] = make_float4(0.f, 0.f, 0.f, 0.f);
    const float4* Wv = (const float4*)Ws;
    const float4* Xv = (const float4*)Xs;
    for (int kk = 0; kk < 32; ++kk) {
        float4 xv[R];
        #pragma unroll
        for (int r = 0; r < R; ++r) xv[r] = Xv[(ty + TY * r) * 32 + kk];
        #pragma unroll
        for (int j = 0; j < 4; ++j) {
            float4 wv = Wv[(4 * kk + j) * 16 + tx];
            #pragma unroll
            for (int r = 0; r < R; ++r) {
                float xs = j == 0 ? xv[r].x : j == 1 ? xv[r].y : j == 2 ? xv[r].z : xv[r].w;
                acc[r].x += xs * wv.x; acc[r].y += xs * wv.y;
                acc[r].z += xs * wv.z; acc[r].w += xs * wv.w;
            }
        }
    }
    #pragma unroll
    for (int r = 0; r < R; ++r) {
        int row = row0 + ty + TY * r;
        if (row < N) ((float4*)(H + (size_t)row * M + c0))[tx] = acc[r];
    }
}

// ---- aggregation, F=128 (float2 per lane), one wave per node ----
__global__ __launch_bounds__(256) void k_agg128(const float* __restrict__ H,
        const float* __restrict__ dinv, const int* __restrict__ rs,
        const int* __restrict__ esrc, const float* __restrict__ bias,
        float* __restrict__ out, int N, int do_relu) {
    int wid = (blockIdx.x * 256 + threadIdx.x) >> 6;
    if (wid >= N) return;
    int l = threadIdx.x & 63;
    const float2* Hv = (const float2*)H;
    float di = dinv[wid];
    float2 a = Hv[(size_t)wid * 64 + l];
    float accx = di * a.x, accy = di * a.y;
    int s0 = rs[wid], s1 = rs[wid + 1];
    for (int k = s0; k < s1; ++k) {
        int s = esrc[k];
        float w = dinv[s];
        float2 v = Hv[(size_t)s * 64 + l];
        accx += w * v.x;
        accy += w * v.y;
    }
    float2 b = ((const float2*)bias)[l];
    float ox = di * accx + b.x, oy = di * accy + b.y;
    if (do_relu) { ox = fmaxf(ox, 0.f); oy = fmaxf(oy, 0.f); }
    float2 o; o.x = ox; o.y = oy;
    ((float2*)out)[(size_t)wid * 64 + l] = o;
}

// ---- aggregation, F=64 (float per lane), one wave per node ----
__global__ __launch_bounds__(256) void k_agg64(const float* __restrict__ H,
        const float* __restrict__ dinv, const int* __restrict__ rs,
        const int* __restrict__ esrc, const float* __restrict__ bias,
        float* __restrict__ out, int N, int do_relu) {
    int wid = (blockIdx.x * 256 + threadIdx.x) >> 6;
    if (wid >= N) return;
    int l = threadIdx.x & 63;
    float di = dinv[wid];
    float acc = di * H[(size_t)wid * 64 + l];
    int s0 = rs[wid], s1 = rs[wid + 1];
    for (int k = s0; k < s1; ++k) {
        int s = esrc[k];
        acc += dinv[s] * H[(size_t)s * 64 + l];
    }
    float o = di * acc + bias[l];
    if (do_relu) o = fmaxf(o, 0.f);
    out[(size_t)wid * 64 + l] = o;
}

extern "C" void kernel_launch(void* const* d_in, const int* in_sizes, int n_in,
                              void* d_out, int out_size, void* d_ws, size_t ws_size,
                              hipStream_t stream) {
    const float* x  = (const float*)d_in[0];
    const void*  ei = d_in[1];
    const float* W1 = (const float*)d_in[2];
    const float* b1 = (const float*)d_in[3];
    const float* W2 = (const float*)d_in[4];
    const float* b2 = (const float*)d_in[5];

    const int HID = in_sizes[3];            // 128
    const int IN  = in_sizes[2] / HID;      // 128
    const int OUT = in_sizes[4] / HID;      // 64
    const int N   = in_sizes[0] / IN;       // 50000
    const int E   = in_sizes[1] / 2;        // 800000

    char* p = (char*)d_ws;
    int* is32      = (int*)p;   p += 256;
    int* counts    = (int*)p;   p += align256((size_t)N * 4);
    int* row_start = (int*)p;   p += align256((size_t)(N + 1) * 4);
    int* pos       = (int*)p;   p += align256((size_t)N * 4);
    int* esrc      = (int*)p;   p += align256((size_t)E * 4);
    float* dinv    = (float*)p; p += align256((size_t)N * 4);
    float* h       = (float*)p; p += align256((size_t)N * HID * 4);
    float* h1      = (float*)p; p += align256((size_t)N * HID * 4);
    float* h2      = (float*)p; p += align256((size_t)N * OUT * 4);

    hipMemsetAsync(is32, 0, 256, stream);
    hipMemsetAsync(counts, 0, (size_t)N * 4, stream);

    k_detect<<<4, 256, 0, stream>>>((const long long*)ei, 1024, is32);
    k_count<<<(E + 255) / 256, 256, 0, stream>>>(ei, E, is32, counts);
    k_dinv<<<(N + 255) / 256, 256, 0, stream>>>(counts, dinv, N);
    k_scan<<<1, 1024, 0, stream>>>(counts, row_start, pos, N);
    k_fill<<<(E + 255) / 256, 256, 0, stream>>>(ei, E, is32, pos, esrc);

    // layer 1: h = x @ W1 ; h1 = relu(agg(h) + b1)
    k_gemm<128><<<dim3((N + 47) / 48, 2), 256, 0, stream>>>(x, W1, h, N);
    k_agg128<<<(N + 3) / 4, 256, 0, stream>>>(h, dinv, row_start, esrc, b1, h1, N, 1);

    // layer 2: h2 = h1 @ W2 ; out = agg(h2) + b2
    k_gemm<64><<<dim3((N + 47) / 48, 1), 256, 0, stream>>>(h1, W2, h2, N);
    k_agg64<<<(N + 3) / 4, 256, 0, stream>>>(h2, dinv, row_start, esrc, b2, (float*)d_out, N, 0);
}

// Round 2
// 439.009 us; speedup vs baseline: 2.6126x; 2.6126x over previous
//
#include <hip/hip_runtime.h>
#include <stdint.h>

static inline size_t align256(size_t x) { return (x + 255) & ~size_t(255); }

// ---- edge dtype detection: is the edge_index buffer int32 or int64? ----
__global__ void k_detect(const long long* __restrict__ e, int n_check, int* __restrict__ is32) {
    int i = blockIdx.x * blockDim.x + threadIdx.x;
    if (i < n_check) {
        long long v = e[i];
        if (v < 0 || v > 0x7fffffffLL) atomicOr(is32, 1);
    }
}

// ---- count in-degree on dst ----
__global__ void k_count(const void* __restrict__ eidx, int E, const int* __restrict__ is32,
                        int* __restrict__ counts) {
    int e = blockIdx.x * blockDim.x + threadIdx.x;
    if (e >= E) return;
    int d;
    if (*is32) d = ((const int*)eidx)[(size_t)E + e];
    else       d = (int)((const long long*)eidx)[(size_t)E + e];
    atomicAdd(&counts[d], 1);
}

__global__ void k_dinv(const int* __restrict__ counts, float* __restrict__ dinv, int N) {
    int i = blockIdx.x * blockDim.x + threadIdx.x;
    if (i < N) dinv[i] = rsqrtf((float)counts[i] + 1.0f);
}

// ---- single-block exclusive scan of counts -> row_start[N+1], pos[N] ----
__global__ __launch_bounds__(1024) void k_scan(const int* __restrict__ counts,
                                               int* __restrict__ row_start,
                                               int* __restrict__ pos, int N) {
    __shared__ int swt[16];
    __shared__ int swt2[16];
    const int t = threadIdx.x, lane = t & 63, w = t >> 6;
    int carry = 0;
    for (int base = 0; base < N; base += 1024) {
        int i = base + t;
        int v = (i < N) ? counts[i] : 0;
        int incl = v;
        #pragma unroll
        for (int off = 1; off < 64; off <<= 1) {
            int nbr = __shfl_up(incl, off, 64);
            if (lane >= off) incl += nbr;
        }
        if (lane == 63) swt[w] = incl;
        __syncthreads();
        if (w == 0) {
            int wincl = (lane < 16) ? swt[lane] : 0;
            #pragma unroll
            for (int off = 1; off < 16; off <<= 1) {
                int nbr = __shfl_up(wincl, off, 64);
                if (lane >= off) wincl += nbr;
            }
            if (lane < 16) swt2[lane] = wincl;
        }
        __syncthreads();
        int wave_off = (w == 0) ? 0 : swt2[w - 1];
        int excl = carry + wave_off + incl - v;
        if (i < N) { row_start[i] = excl; pos[i] = excl; }
        carry += swt2[15];
        __syncthreads();
    }
    if (t == 0) row_start[N] = carry;
}

// ---- fill CSR: esrc sorted by dst ----
__global__ void k_fill(const void* __restrict__ eidx, int E, const int* __restrict__ is32,
                       int* __restrict__ pos, int* __restrict__ esrc) {
    int e = blockIdx.x * blockDim.x + threadIdx.x;
    if (e >= E) return;
    int s, d;
    if (*is32) {
        s = ((const int*)eidx)[e];
        d = ((const int*)eidx)[(size_t)E + e];
    } else {
        s = (int)((const long long*)eidx)[e];
        d = (int)((const long long*)eidx)[(size_t)E + e];
    }
    int p = atomicAdd(&pos[d], 1);
    esrc[p] = s;
}

// ---- fp32 GEMM: H[N x M] = X[N x 128] @ W[128 x M] ----
// Block: 256 threads, 128 rows x 64 cols tile. Thread: 8 rows x 4 cols.
// As transposed [BK][BM+4] for vectorized row-fragment reads; Ws natural [BK][BN].
// ~70 VGPR target; __launch_bounds__(256,4) caps at 128 to prevent spill.
template<int M>
__global__ __launch_bounds__(256, 4) void k_gemm(const float* __restrict__ X,
                                                 const float* __restrict__ W,
                                                 float* __restrict__ H, int N) {
    constexpr int K = 128;
    constexpr int BM = 128, BN = 64, BK = 32;
    constexpr int LDA = BM + 4;       // 132: 16B-aligned stride, stage-writes <=4-way conflict
    __shared__ float As[BK * LDA];    // 16.5 KB, As[k][row]
    __shared__ float Ws[BK * BN];     // 8 KB,   Ws[k][col]
    const int tid = threadIdx.x;
    const int tx = tid & 15;          // thread-col: 4 consecutive cols
    const int ty = tid >> 4;          // thread-row: 8 consecutive rows
    const int row0 = blockIdx.x * BM;
    const int c0 = blockIdx.y * BN;

    float4 acc[8];
    #pragma unroll
    for (int r = 0; r < 8; ++r) acc[r] = make_float4(0.f, 0.f, 0.f, 0.f);

    for (int kc = 0; kc < K / BK; ++kc) {
        // stage A transposed: 128 rows x 8 float4 (1024 float4s / 256 thr = 4 iters)
        #pragma unroll
        for (int it = 0; it < 4; ++it) {
            int i = tid + it * 256;
            int r = i >> 3, c = i & 7;
            int row = row0 + r;
            float4 v = make_float4(0.f, 0.f, 0.f, 0.f);
            if (row < N) v = ((const float4*)X)[(size_t)row * (K / 4) + kc * (BK / 4) + c];
            int kk = c * 4;
            As[(kk + 0) * LDA + r] = v.x;
            As[(kk + 1) * LDA + r] = v.y;
            As[(kk + 2) * LDA + r] = v.z;
            As[(kk + 3) * LDA + r] = v.w;
        }
        // stage W: 32 x 64 floats (512 float4s / 256 thr = 2 iters)
        #pragma unroll
        for (int it = 0; it < 2; ++it) {
            int i = tid + it * 256;
            int k = i >> 4, c4 = i & 15;
            ((float4*)Ws)[i] = ((const float4*)(W + (size_t)(kc * BK + k) * M + c0))[c4];
        }
        __syncthreads();
        #pragma unroll 4
        for (int k = 0; k < BK; ++k) {
            float4 a0 = *(const float4*)&As[k * LDA + ty * 8];
            float4 a1 = *(const float4*)&As[k * LDA + ty * 8 + 4];
            float4 b  = *(const float4*)&Ws[k * BN + tx * 4];
            float ar[8] = {a0.x, a0.y, a0.z, a0.w, a1.x, a1.y, a1.z, a1.w};
            #pragma unroll
            for (int r = 0; r < 8; ++r) {
                acc[r].x = fmaf(ar[r], b.x, acc[r].x);
                acc[r].y = fmaf(ar[r], b.y, acc[r].y);
                acc[r].z = fmaf(ar[r], b.z, acc[r].z);
                acc[r].w = fmaf(ar[r], b.w, acc[r].w);
            }
        }
        __syncthreads();
    }
    #pragma unroll
    for (int r = 0; r < 8; ++r) {
        int row = row0 + ty * 8 + r;
        if (row < N) *(float4*)&H[(size_t)row * M + c0 + tx * 4] = acc[r];
    }
}

// ---- aggregation, F=128 (float2 per lane), one wave per node ----
__global__ __launch_bounds__(256) void k_agg128(const float* __restrict__ H,
        const float* __restrict__ dinv, const int* __restrict__ rs,
        const int* __restrict__ esrc, const float* __restrict__ bias,
        float* __restrict__ out, int N, int do_relu) {
    int wid = (blockIdx.x * 256 + threadIdx.x) >> 6;
    if (wid >= N) return;
    int l = threadIdx.x & 63;
    const float2* Hv = (const float2*)H;
    float di = dinv[wid];
    float2 a = Hv[(size_t)wid * 64 + l];
    float accx = di * a.x, accy = di * a.y;
    int s0 = rs[wid], s1 = rs[wid + 1];
    for (int k = s0; k < s1; ++k) {
        int s = esrc[k];
        float w = dinv[s];
        float2 v = Hv[(size_t)s * 64 + l];
        accx += w * v.x;
        accy += w * v.y;
    }
    float2 b = ((const float2*)bias)[l];
    float ox = di * accx + b.x, oy = di * accy + b.y;
    if (do_relu) { ox = fmaxf(ox, 0.f); oy = fmaxf(oy, 0.f); }
    float2 o; o.x = ox; o.y = oy;
    ((float2*)out)[(size_t)wid * 64 + l] = o;
}

// ---- aggregation, F=64 (float per lane), one wave per node ----
__global__ __launch_bounds__(256) void k_agg64(const float* __restrict__ H,
        const float* __restrict__ dinv, const int* __restrict__ rs,
        const int* __restrict__ esrc, const float* __restrict__ bias,
        float* __restrict__ out, int N, int do_relu) {
    int wid = (blockIdx.x * 256 + threadIdx.x) >> 6;
    if (wid >= N) return;
    int l = threadIdx.x & 63;
    float di = dinv[wid];
    float acc = di * H[(size_t)wid * 64 + l];
    int s0 = rs[wid], s1 = rs[wid + 1];
    for (int k = s0; k < s1; ++k) {
        int s = esrc[k];
        acc += dinv[s] * H[(size_t)s * 64 + l];
    }
    float o = di * acc + bias[l];
    if (do_relu) o = fmaxf(o, 0.f);
    out[(size_t)wid * 64 + l] = o;
}

extern "C" void kernel_launch(void* const* d_in, const int* in_sizes, int n_in,
                              void* d_out, int out_size, void* d_ws, size_t ws_size,
                              hipStream_t stream) {
    const float* x  = (const float*)d_in[0];
    const void*  ei = d_in[1];
    const float* W1 = (const float*)d_in[2];
    const float* b1 = (const float*)d_in[3];
    const float* W2 = (const float*)d_in[4];
    const float* b2 = (const float*)d_in[5];

    const int HID = in_sizes[3];            // 128
    const int IN  = in_sizes[2] / HID;      // 128
    const int OUT = in_sizes[4] / HID;      // 64
    const int N   = in_sizes[0] / IN;       // 50000
    const int E   = in_sizes[1] / 2;        // 800000

    char* p = (char*)d_ws;
    int* is32      = (int*)p;   p += 256;
    int* counts    = (int*)p;   p += align256((size_t)N * 4);
    int* row_start = (int*)p;   p += align256((size_t)(N + 1) * 4);
    int* pos       = (int*)p;   p += align256((size_t)N * 4);
    int* esrc      = (int*)p;   p += align256((size_t)E * 4);
    float* dinv    = (float*)p; p += align256((size_t)N * 4);
    float* h       = (float*)p; p += align256((size_t)N * HID * 4);
    float* h1      = (float*)p; p += align256((size_t)N * HID * 4);
    float* h2      = (float*)p; p += align256((size_t)N * OUT * 4);

    hipMemsetAsync(is32, 0, 256, stream);
    hipMemsetAsync(counts, 0, (size_t)N * 4, stream);

    k_detect<<<4, 256, 0, stream>>>((const long long*)ei, 1024, is32);
    k_count<<<(E + 255) / 256, 256, 0, stream>>>(ei, E, is32, counts);
    k_dinv<<<(N + 255) / 256, 256, 0, stream>>>(counts, dinv, N);
    k_scan<<<1, 1024, 0, stream>>>(counts, row_start, pos, N);
    k_fill<<<(E + 255) / 256, 256, 0, stream>>>(ei, E, is32, pos, esrc);

    // layer 1: h = x @ W1 ; h1 = relu(agg(h) + b1)
    k_gemm<128><<<dim3((N + 127) / 128, 2), 256, 0, stream>>>(x, W1, h, N);
    k_agg128<<<(N + 3) / 4, 256, 0, stream>>>(h, dinv, row_start, esrc, b1, h1, N, 1);

    // layer 2: h2 = h1 @ W2 ; out = agg(h2) + b2
    k_gemm<64><<<dim3((N + 127) / 128, 1), 256, 0, stream>>>(h1, W2, h2, N);
    k_agg64<<<(N + 3) / 4, 256, 0, stream>>>(h2, dinv, row_start, esrc, b2, (float*)d_out, N, 0);
}

// Round 3
// 303.347 us; speedup vs baseline: 3.7809x; 1.4472x over previous
//
#include <hip/hip_runtime.h>
#include <stdint.h>

static inline size_t align256(size_t x) { return (x + 255) & ~size_t(255); }

__device__ __forceinline__ unsigned short f2bf(float f) {
    unsigned u = __float_as_uint(f);
    u += 0x7fff + ((u >> 16) & 1);     // round-to-nearest-even
    return (unsigned short)(u >> 16);
}
__device__ __forceinline__ unsigned pack_bf16(float a, float b) {
    return (unsigned)f2bf(a) | ((unsigned)f2bf(b) << 16);
}
__device__ __forceinline__ float bf_lo(unsigned u) { return __uint_as_float(u << 16); }
__device__ __forceinline__ float bf_hi(unsigned u) { return __uint_as_float(u & 0xffff0000u); }

// ---- edge dtype detection: is the edge_index buffer int32 or int64? ----
__global__ void k_detect(const long long* __restrict__ e, int n_check, int* __restrict__ is32) {
    int i = blockIdx.x * blockDim.x + threadIdx.x;
    if (i < n_check) {
        long long v = e[i];
        if (v < 0 || v > 0x7fffffffLL) atomicOr(is32, 1);
    }
}

// ---- count in-degree on dst ----
__global__ void k_count(const void* __restrict__ eidx, int E, const int* __restrict__ is32,
                        int* __restrict__ counts) {
    int e = blockIdx.x * blockDim.x + threadIdx.x;
    if (e >= E) return;
    int d;
    if (*is32) d = ((const int*)eidx)[(size_t)E + e];
    else       d = (int)((const long long*)eidx)[(size_t)E + e];
    atomicAdd(&counts[d], 1);
}

__global__ void k_dinv(const int* __restrict__ counts, float* __restrict__ dinv, int N) {
    int i = blockIdx.x * blockDim.x + threadIdx.x;
    if (i < N) dinv[i] = rsqrtf((float)counts[i] + 1.0f);
}

// ---- hierarchical exclusive scan: pass 1 (per-block local scan of 1024 elems) ----
__global__ __launch_bounds__(1024) void k_scan1(const int* __restrict__ counts,
                                                int* __restrict__ row_start,
                                                int* __restrict__ bsum, int N) {
    __shared__ int swt[16];
    __shared__ int swt2[16];
    const int t = threadIdx.x, lane = t & 63, w = t >> 6;
    int i = blockIdx.x * 1024 + t;
    int v = (i < N) ? counts[i] : 0;
    int incl = v;
    #pragma unroll
    for (int off = 1; off < 64; off <<= 1) {
        int nbr = __shfl_up(incl, off, 64);
        if (lane >= off) incl += nbr;
    }
    if (lane == 63) swt[w] = incl;
    __syncthreads();
    if (w == 0) {
        int wincl = (lane < 16) ? swt[lane] : 0;
        #pragma unroll
        for (int off = 1; off < 16; off <<= 1) {
            int nbr = __shfl_up(wincl, off, 64);
            if (lane >= off) wincl += nbr;
        }
        if (lane < 16) swt2[lane] = wincl;
    }
    __syncthreads();
    int excl = ((w == 0) ? 0 : swt2[w - 1]) + incl - v;
    if (i < N) row_start[i] = excl;
    if (t == 0) bsum[blockIdx.x] = swt2[15];
}

// ---- pass 2: single-block scan of block sums (nblk <= a few thousand) ----
__global__ __launch_bounds__(1024) void k_scan2(const int* __restrict__ bsum,
                                                int* __restrict__ bexc,
                                                int* __restrict__ row_start,
                                                int nblk, int N) {
    __shared__ int swt[16];
    __shared__ int swt2[16];
    const int t = threadIdx.x, lane = t & 63, w = t >> 6;
    int carry = 0;
    for (int base = 0; base < nblk; base += 1024) {
        int i = base + t;
        int v = (i < nblk) ? bsum[i] : 0;
        int incl = v;
        #pragma unroll
        for (int off = 1; off < 64; off <<= 1) {
            int nbr = __shfl_up(incl, off, 64);
            if (lane >= off) incl += nbr;
        }
        if (lane == 63) swt[w] = incl;
        __syncthreads();
        if (w == 0) {
            int wincl = (lane < 16) ? swt[lane] : 0;
            #pragma unroll
            for (int off = 1; off < 16; off <<= 1) {
                int nbr = __shfl_up(wincl, off, 64);
                if (lane >= off) wincl += nbr;
            }
            if (lane < 16) swt2[lane] = wincl;
        }
        __syncthreads();
        int excl = carry + ((w == 0) ? 0 : swt2[w - 1]) + incl - v;
        if (i < nblk) bexc[i] = excl;
        carry += swt2[15];
        __syncthreads();
    }
    if (t == 0) row_start[N] = carry;
}

// ---- pass 3: add block offsets; init pos ----
__global__ void k_scan3(int* __restrict__ row_start, int* __restrict__ pos,
                        const int* __restrict__ bexc, int N) {
    int i = blockIdx.x * blockDim.x + threadIdx.x;
    if (i < N) {
        int r = row_start[i] + bexc[i >> 10];
        row_start[i] = r;
        pos[i] = r;
    }
}

// ---- fill CSR: esrc sorted by dst ----
__global__ void k_fill(const void* __restrict__ eidx, int E, const int* __restrict__ is32,
                       int* __restrict__ pos, int* __restrict__ esrc) {
    int e = blockIdx.x * blockDim.x + threadIdx.x;
    if (e >= E) return;
    int s, d;
    if (*is32) {
        s = ((const int*)eidx)[e];
        d = ((const int*)eidx)[(size_t)E + e];
    } else {
        s = (int)((const long long*)eidx)[e];
        d = (int)((const long long*)eidx)[(size_t)E + e];
    }
    int p = atomicAdd(&pos[d], 1);
    esrc[p] = s;
}

// ---- fp32 GEMM, bf16 output: Hb[N x M](bf16) = X[N x 128] @ W[128 x M] ----
// Block: 256 threads, 128 rows x 64 cols tile. Thread: 8 rows x 4 cols. ~70 VGPR.
template<int M>
__global__ __launch_bounds__(256, 4) void k_gemm(const float* __restrict__ X,
                                                 const float* __restrict__ W,
                                                 unsigned* __restrict__ Hb, int N) {
    constexpr int K = 128;
    constexpr int BM = 128, BN = 64, BK = 32;
    constexpr int LDA = BM + 4;
    __shared__ float As[BK * LDA];    // 16.5 KB, As[k][row]
    __shared__ float Ws[BK * BN];     // 8 KB,   Ws[k][col]
    const int tid = threadIdx.x;
    const int tx = tid & 15;
    const int ty = tid >> 4;
    const int row0 = blockIdx.x * BM;
    const int c0 = blockIdx.y * BN;

    float4 acc[8];
    #pragma unroll
    for (int r = 0; r < 8; ++r) acc[r] = make_float4(0.f, 0.f, 0.f, 0.f);

    for (int kc = 0; kc < K / BK; ++kc) {
        #pragma unroll
        for (int it = 0; it < 4; ++it) {
            int i = tid + it * 256;
            int r = i >> 3, c = i & 7;
            int row = row0 + r;
            float4 v = make_float4(0.f, 0.f, 0.f, 0.f);
            if (row < N) v = ((const float4*)X)[(size_t)row * (K / 4) + kc * (BK / 4) + c];
            int kk = c * 4;
            As[(kk + 0) * LDA + r] = v.x;
            As[(kk + 1) * LDA + r] = v.y;
            As[(kk + 2) * LDA + r] = v.z;
            As[(kk + 3) * LDA + r] = v.w;
        }
        #pragma unroll
        for (int it = 0; it < 2; ++it) {
            int i = tid + it * 256;
            int k = i >> 4, c4 = i & 15;
            ((float4*)Ws)[i] = ((const float4*)(W + (size_t)(kc * BK + k) * M + c0))[c4];
        }
        __syncthreads();
        #pragma unroll 4
        for (int k = 0; k < BK; ++k) {
            float4 a0 = *(const float4*)&As[k * LDA + ty * 8];
            float4 a1 = *(const float4*)&As[k * LDA + ty * 8 + 4];
            float4 b  = *(const float4*)&Ws[k * BN + tx * 4];
            float ar[8] = {a0.x, a0.y, a0.z, a0.w, a1.x, a1.y, a1.z, a1.w};
            #pragma unroll
            for (int r = 0; r < 8; ++r) {
                acc[r].x = fmaf(ar[r], b.x, acc[r].x);
                acc[r].y = fmaf(ar[r], b.y, acc[r].y);
                acc[r].z = fmaf(ar[r], b.z, acc[r].z);
                acc[r].w = fmaf(ar[r], b.w, acc[r].w);
            }
        }
        __syncthreads();
    }
    #pragma unroll
    for (int r = 0; r < 8; ++r) {
        int row = row0 + ty * 8 + r;
        if (row < N) {
            uint2 o;
            o.x = pack_bf16(acc[r].x, acc[r].y);
            o.y = pack_bf16(acc[r].z, acc[r].w);
            *(uint2*)&Hb[((size_t)row * M + c0 + tx * 4) >> 1] = o;
        }
    }
}

// ---- aggregation, F=128, bf16 gather source, fp32 out; one wave per node ----
__global__ __launch_bounds__(256) void k_agg128(const unsigned* __restrict__ Hb,
        const float* __restrict__ dinv, const int* __restrict__ rs,
        const int* __restrict__ esrc, const float* __restrict__ bias,
        float* __restrict__ out, int N) {
    int wid = (blockIdx.x * 256 + threadIdx.x) >> 6;
    if (wid >= N) return;
    int l = threadIdx.x & 63;
    float di = dinv[wid];
    unsigned a = Hb[(size_t)wid * 64 + l];
    float accx = di * bf_lo(a), accy = di * bf_hi(a);
    int k = rs[wid], kend = rs[wid + 1];
    for (; k + 4 <= kend; k += 4) {
        int sA = esrc[k], sB = esrc[k + 1], sC = esrc[k + 2], sD = esrc[k + 3];
        float wA = dinv[sA], wB = dinv[sB], wC = dinv[sC], wD = dinv[sD];
        unsigned gA = Hb[(size_t)sA * 64 + l];
        unsigned gB = Hb[(size_t)sB * 64 + l];
        unsigned gC = Hb[(size_t)sC * 64 + l];
        unsigned gD = Hb[(size_t)sD * 64 + l];
        accx = fmaf(wA, bf_lo(gA), accx); accy = fmaf(wA, bf_hi(gA), accy);
        accx = fmaf(wB, bf_lo(gB), accx); accy = fmaf(wB, bf_hi(gB), accy);
        accx = fmaf(wC, bf_lo(gC), accx); accy = fmaf(wC, bf_hi(gC), accy);
        accx = fmaf(wD, bf_lo(gD), accx); accy = fmaf(wD, bf_hi(gD), accy);
    }
    for (; k < kend; ++k) {
        int s = esrc[k];
        float w = dinv[s];
        unsigned g = Hb[(size_t)s * 64 + l];
        accx = fmaf(w, bf_lo(g), accx);
        accy = fmaf(w, bf_hi(g), accy);
    }
    float2 b = ((const float2*)bias)[l];
    float2 o;
    o.x = fmaxf(fmaf(di, accx, b.x), 0.f);   // layer 1 always has ReLU
    o.y = fmaxf(fmaf(di, accy, b.y), 0.f);
    ((float2*)out)[(size_t)wid * 64 + l] = o;
}

// ---- aggregation, F=64, bf16 gather source (ushort/lane); one wave per node ----
__global__ __launch_bounds__(256) void k_agg64(const unsigned short* __restrict__ Hb,
        const float* __restrict__ dinv, const int* __restrict__ rs,
        const int* __restrict__ esrc, const float* __restrict__ bias,
        float* __restrict__ out, int N) {
    int wid = (blockIdx.x * 256 + threadIdx.x) >> 6;
    if (wid >= N) return;
    int l = threadIdx.x & 63;
    float di = dinv[wid];
    float acc = di * __uint_as_float((unsigned)Hb[(size_t)wid * 64 + l] << 16);
    int k = rs[wid], kend = rs[wid + 1];
    for (; k + 4 <= kend; k += 4) {
        int sA = esrc[k], sB = esrc[k + 1], sC = esrc[k + 2], sD = esrc[k + 3];
        float wA = dinv[sA], wB = dinv[sB], wC = dinv[sC], wD = dinv[sD];
        float gA = __uint_as_float((unsigned)Hb[(size_t)sA * 64 + l] << 16);
        float gB = __uint_as_float((unsigned)Hb[(size_t)sB * 64 + l] << 16);
        float gC = __uint_as_float((unsigned)Hb[(size_t)sC * 64 + l] << 16);
        float gD = __uint_as_float((unsigned)Hb[(size_t)sD * 64 + l] << 16);
        acc = fmaf(wA, gA, acc); acc = fmaf(wB, gB, acc);
        acc = fmaf(wC, gC, acc); acc = fmaf(wD, gD, acc);
    }
    for (; k < kend; ++k) {
        int s = esrc[k];
        acc = fmaf(dinv[s], __uint_as_float((unsigned)Hb[(size_t)s * 64 + l] << 16), acc);
    }
    out[(size_t)wid * 64 + l] = fmaf(di, acc, bias[l]);   // layer 2: no ReLU
}

extern "C" void kernel_launch(void* const* d_in, const int* in_sizes, int n_in,
                              void* d_out, int out_size, void* d_ws, size_t ws_size,
                              hipStream_t stream) {
    const float* x  = (const float*)d_in[0];
    const void*  ei = d_in[1];
    const float* W1 = (const float*)d_in[2];
    const float* b1 = (const float*)d_in[3];
    const float* W2 = (const float*)d_in[4];
    const float* b2 = (const float*)d_in[5];

    const int HID = in_sizes[3];            // 128
    const int IN  = in_sizes[2] / HID;      // 128
    const int OUT = in_sizes[4] / HID;      // 64
    const int N   = in_sizes[0] / IN;       // 50000
    const int E   = in_sizes[1] / 2;        // 800000
    const int NBLK = (N + 1023) / 1024;

    char* p = (char*)d_ws;
    int* is32      = (int*)p;   p += 256;
    int* counts    = (int*)p;   p += align256((size_t)N * 4);
    int* row_start = (int*)p;   p += align256((size_t)(N + 1) * 4);
    int* pos       = (int*)p;   p += align256((size_t)N * 4);
    int* bsum      = (int*)p;   p += align256((size_t)NBLK * 4);
    int* bexc      = (int*)p;   p += align256((size_t)NBLK * 4);
    int* esrc      = (int*)p;   p += align256((size_t)E * 4);
    float* dinv    = (float*)p; p += align256((size_t)N * 4);
    unsigned* hb   = (unsigned*)p;       p += align256((size_t)N * HID * 2);  // bf16 h
    float* h1      = (float*)p;          p += align256((size_t)N * HID * 4);  // fp32 h1
    unsigned short* h2b = (unsigned short*)p; p += align256((size_t)N * OUT * 2); // bf16 h2

    hipMemsetAsync(is32, 0, 256, stream);
    hipMemsetAsync(counts, 0, (size_t)N * 4, stream);

    k_detect<<<4, 256, 0, stream>>>((const long long*)ei, 1024, is32);
    k_count<<<(E + 255) / 256, 256, 0, stream>>>(ei, E, is32, counts);
    k_dinv<<<(N + 255) / 256, 256, 0, stream>>>(counts, dinv, N);
    k_scan1<<<NBLK, 1024, 0, stream>>>(counts, row_start, bsum, N);
    k_scan2<<<1, 1024, 0, stream>>>(bsum, bexc, row_start, NBLK, N);
    k_scan3<<<(N + 255) / 256, 256, 0, stream>>>(row_start, pos, bexc, N);
    k_fill<<<(E + 255) / 256, 256, 0, stream>>>(ei, E, is32, pos, esrc);

    // layer 1: hb = bf16(x @ W1) ; h1 = relu(agg(hb) + b1)
    k_gemm<128><<<dim3((N + 127) / 128, 2), 256, 0, stream>>>(x, W1, hb, N);
    k_agg128<<<(N + 3) / 4, 256, 0, stream>>>(hb, dinv, row_start, esrc, b1, h1, N);

    // layer 2: h2b = bf16(h1 @ W2) ; out = agg(h2b) + b2
    k_gemm<64><<<dim3((N + 127) / 128, 1), 256, 0, stream>>>(h1, W2, (unsigned*)h2b, N);
    k_agg64<<<(N + 3) / 4, 256, 0, stream>>>(h2b, dinv, row_start, esrc, b2, (float*)d_out, N);
}